// Round 2
// baseline (400.399 us; speedup 1.0000x reference)
//
#include <hip/hip_runtime.h>

#define DD 256
#define KK 32
#define HH 16
#define RR 16
#define BB 64
#define NJ 32      // 2 query sets * 16 heads
#define SPOOL 8
#define SFEAT 8

// ---------------- kernel 1: segment firsts (batch_ids is sorted) -------------
__global__ void k_firsts(const int* __restrict__ bid, int* __restrict__ firsts, int N) {
    int i = blockIdx.x * 256 + threadIdx.x;
    if (i >= N) return;
    if (i == 0 || bid[i] != bid[i - 1]) firsts[bid[i]] = i;
}

// ---------------- kernel 2: partial segment max --------------------------------
__global__ void k_pool(const float* __restrict__ inp, const int* __restrict__ firsts,
                       float* __restrict__ poolpart, int N) {
    int s = blockIdx.x, b = blockIdx.y, t = threadIdx.x;
    int first = firsts[b];
    int end = (b == BB - 1) ? N : firsts[b + 1];
    float m = -1e30f;
    for (int n = first + s; n < end; n += SPOOL)
        m = fmaxf(m, inp[(size_t)n * DD + t]);
    poolpart[((size_t)b * SPOOL + s) * DD + t] = m;
}

// ---------------- kernel 3: reduce pool + q = pooled @ Wq^T --------------------
__global__ void k_q(const float* __restrict__ poolpart,
                    const float* __restrict__ Wq0, const float* __restrict__ Wq1,
                    float* __restrict__ qbuf) {
    int b = blockIdx.x, t = threadIdx.x;
    __shared__ float pooled[DD];
    float m = -1e30f;
    for (int s = 0; s < SPOOL; ++s)
        m = fmaxf(m, poolpart[((size_t)b * SPOOL + s) * DD + t]);
    pooled[t] = m;
    __syncthreads();
    // 1024 outputs: idx = set*512 + h*32 + k  ==  j*32 + k with j = set*16+h
    for (int c = 0; c < 4; ++c) {
        int idx = c * 256 + t;
        const float* W = (idx < 512) ? Wq0 : Wq1;
        int row = idx & 511;
        const float* wr = W + (size_t)row * DD;
        float acc = 0.f;
        for (int d = 0; d < DD; ++d) acc += pooled[d] * wr[d];
        qbuf[(size_t)b * 1024 + idx] = acc;
    }
}

// ---------------- kernel 4: keys + scores (fused, per 16-node tile) ------------
__global__ void k_scores(const float* __restrict__ inp, const int* __restrict__ bid,
                         const float* __restrict__ Wk, const float* __restrict__ qbuf,
                         float* __restrict__ scores, int N) {
    __shared__ float Xs[16][DD];
    __shared__ float Wks[KK * 257];
    __shared__ float keys[16][KK];
    int t = threadIdx.x;
    int n0 = blockIdx.x * 16;
    for (int idx = t; idx < KK * DD; idx += 256) {
        int k = idx >> 8, d = idx & 255;
        Wks[k * 257 + d] = Wk[idx];
    }
    for (int i = 0; i < 16; ++i) {
        int n = n0 + i;
        Xs[i][t] = (n < N) ? inp[(size_t)n * DD + t] : 0.f;
    }
    __syncthreads();
    for (int it = 0; it < 2; ++it) {
        int nl = (t >> 5) + it * 8;
        int k = t & 31;
        float acc = 0.f;
        for (int d = 0; d < DD; ++d) acc += Xs[nl][d] * Wks[k * 257 + d];
        keys[nl][k] = acc;
    }
    __syncthreads();
    for (int it = 0; it < 2; ++it) {
        int nl = (t >> 5) + it * 8;
        int j = t & 31;
        int n = n0 + nl;
        if (n < N) {
            int b = bid[n];
            const float* q = qbuf + (size_t)b * 1024 + j * 32;
            float acc = 0.f;
            for (int k = 0; k < KK; ++k) acc += q[k] * keys[nl][k];
            scores[(size_t)n * NJ + j] = acc;
        }
    }
}

// ---------------- kernel 5: per-(graph, j) online softmax stats ----------------
__global__ void k_stats(const float* __restrict__ scores, const int* __restrict__ firsts,
                        float* __restrict__ smax, float* __restrict__ ssum, int N) {
    int b = blockIdx.x, t = threadIdx.x;
    int j = t & 31, g = t >> 5;
    int first = firsts[b];
    int end = (b == BB - 1) ? N : firsts[b + 1];
    float m = -1e30f, s = 0.f;
    for (int n = first + g; n < end; n += 8) {
        float v = scores[(size_t)n * NJ + j];
        float nm = fmaxf(m, v);
        s = s * __expf(m - nm) + __expf(v - nm);
        m = nm;
    }
    __shared__ float mred[8][32], sred[8][32];
    mred[g][j] = m;
    sred[g][j] = s;
    __syncthreads();
    if (t < 32) {
        float M = -1e30f;
        for (int g2 = 0; g2 < 8; ++g2) M = fmaxf(M, mred[g2][t]);
        float S = 0.f;
        for (int g2 = 0; g2 < 8; ++g2) S += sred[g2][t] * __expf(mred[g2][t] - M);
        smax[b * NJ + t] = M;
        ssum[b * NJ + t] = S;
    }
}

// ---------------- kernel 6: partial attention-weighted feature sums ------------
__global__ void k_feat(const float* __restrict__ inp, const float* __restrict__ scores,
                       const int* __restrict__ firsts, const float* __restrict__ smax,
                       float* __restrict__ featpart, int N) {
    int s = blockIdx.x, b = blockIdx.y, t = threadIdx.x;
    int first = firsts[b];
    int end = (b == BB - 1) ? N : firsts[b + 1];
    __shared__ float es[8][32];
    float facc[NJ];
#pragma unroll
    for (int j = 0; j < NJ; ++j) facc[j] = 0.f;
    int nl = t >> 5, jj = t & 31;
    float mj = smax[b * NJ + jj];
    for (int cs = first + s * 8; cs < end; cs += SFEAT * 8) {
        __syncthreads();
        int n = cs + nl;
        es[nl][jj] = (n < end) ? __expf(scores[(size_t)n * NJ + jj] - mj) : 0.f;
        __syncthreads();
#pragma unroll 1
        for (int q = 0; q < 8; ++q) {
            int nn = cs + q;
            if (nn >= end) break;
            float x = inp[(size_t)nn * DD + t];
            const float4* e4 = (const float4*)es[q];
#pragma unroll
            for (int j4 = 0; j4 < 8; ++j4) {
                float4 e = e4[j4];
                facc[j4 * 4 + 0] += e.x * x;
                facc[j4 * 4 + 1] += e.y * x;
                facc[j4 * 4 + 2] += e.z * x;
                facc[j4 * 4 + 3] += e.w * x;
            }
        }
    }
#pragma unroll
    for (int j = 0; j < NJ; ++j)
        featpart[(((size_t)b * SFEAT + s) * NJ + j) * DD + t] = facc[j];
}

// ---------------- kernel 7: reduce + normalize + embed + dx + out --------------
__global__ void k_final(const float* __restrict__ featpart, const float* __restrict__ ssum,
                        const float* __restrict__ Wemb, const float* __restrict__ Wout,
                        const float* __restrict__ bout, float* __restrict__ out) {
    int b = blockIdx.x, t = threadIdx.x;
    __shared__ float feats[NJ][DD + 1];
    __shared__ float emb[NJ * RR];
    __shared__ float dxs[256];
    for (int j = 0; j < NJ; ++j) {
        float acc = 0.f;
        for (int s = 0; s < SFEAT; ++s)
            acc += featpart[(((size_t)b * SFEAT + s) * NJ + j) * DD + t];
        feats[j][t] = acc / ssum[b * NJ + j];
    }
    __syncthreads();
    for (int c = 0; c < 2; ++c) {
        int o = c * 256 + t;      // 0..511 : j = o>>4 (0..31), r = o&15
        int j = o >> 4, r = o & 15;
        const float* wr = Wemb + (size_t)r * DD;
        float acc = 0.f;
        for (int d = 0; d < DD; ++d) acc += feats[j][d] * wr[d];
        emb[o] = acc;
    }
    __syncthreads();
    {
        int h = t >> 4, r = t & 15;
        dxs[t] = emb[h * 16 + r] - emb[(16 + h) * 16 + r];
    }
    __syncthreads();
    float acc = bout[t];
    const float* wr = Wout + (size_t)t * 256;
    for (int i = 0; i < 256; ++i) acc += dxs[i] * wr[i];
    out[(size_t)b * DD + t] = (acc > 0.f) ? acc : 0.01f * acc;
}

extern "C" void kernel_launch(void* const* d_in, const int* in_sizes, int n_in,
                              void* d_out, int out_size, void* d_ws, size_t ws_size,
                              hipStream_t stream) {
    const float* inp  = (const float*)d_in[0];
    const int*   bid  = (const int*)d_in[1];
    // d_in[2]=num_graphs(64), d_in[3]=max_nodes(2048): static, hardcoded
    const float* Wk   = (const float*)d_in[4];
    const float* Wq0  = (const float*)d_in[5];
    const float* Wq1  = (const float*)d_in[6];
    const float* Wemb = (const float*)d_in[7];
    const float* Wout = (const float*)d_in[8];
    const float* bout = (const float*)d_in[9];
    float* out = (float*)d_out;

    int N = in_sizes[0] / DD;

    char* ws = (char*)d_ws;
    size_t off = 0;
    int* firsts = (int*)(ws + off);          off += 1024;
    float* poolpart = (float*)(ws + off);    off += (size_t)BB * SPOOL * DD * 4;
    float* qbuf = (float*)(ws + off);        off += (size_t)BB * 1024 * 4;
    float* smax = (float*)(ws + off);        off += (size_t)BB * NJ * 4;
    float* ssum = (float*)(ws + off);        off += (size_t)BB * NJ * 4;
    float* scores = (float*)(ws + off);      off += (size_t)N * NJ * 4;
    float* featpart = (float*)(ws + off);    off += (size_t)BB * SFEAT * NJ * DD * 4;

    hipLaunchKernelGGL(k_firsts, dim3((N + 255) / 256), dim3(256), 0, stream, bid, firsts, N);
    hipLaunchKernelGGL(k_pool, dim3(SPOOL, BB), dim3(256), 0, stream, inp, firsts, poolpart, N);
    hipLaunchKernelGGL(k_q, dim3(BB), dim3(256), 0, stream, poolpart, Wq0, Wq1, qbuf);
    hipLaunchKernelGGL(k_scores, dim3((N + 15) / 16), dim3(256), 0, stream, inp, bid, Wk, qbuf, scores, N);
    hipLaunchKernelGGL(k_stats, dim3(BB), dim3(256), 0, stream, scores, firsts, smax, ssum, N);
    hipLaunchKernelGGL(k_feat, dim3(SFEAT, BB), dim3(256), 0, stream, inp, scores, firsts, smax, featpart, N);
    hipLaunchKernelGGL(k_final, dim3(BB), dim3(256), 0, stream, featpart, ssum, Wemb, Wout, bout, out);
}